// Round 6
// baseline (714.122 us; speedup 1.0000x reference)
//
#include <hip/hip_runtime.h>
#include <math.h>
#include <stdint.h>

// SLAYER 2-layer SNN. Round 18: split gemm/conv, in-place conv buffer.
//   expand_x -> decompose_i8 x2 ->
//   gemm<1024> -> conv_fir -> scan<BITS->Bexp2> ->
//   gemm<2048> -> conv_fir -> scan<F32>.
// R17 post-mortem: removing the B-unpack VALU made the fused kernel SLOWER
// (308->334us, VALUBusy 31->26.5) -> stall-bound at 2 waves/SIMD, not
// VALU-bound. R16 showed no 3-wave occupancy step exists (168 VGPR ==
// 196 VGPR occupancy); fused kernel needs >128 VGPR -> pinned. R18: split.
//   gemm_i8: GEMM only, two-pass acc[5][2], pre-expanded B, recombine ->
//     LDS -> coalesced fp64 a store. Live set ~90; amdgpu_num_vgpr(128)
//     (exact-apply proven R15/R16) with ~38 slack -> 4 waves/SIMD,
//     matching the 35KB-LDS 4-blocks/CU cap.
//   conv_fir: tile load a -> LDS (full load, barrier) -> verified FIR ->
//     store u IN PLACE over a (each block owns its slice exclusively).
//     Workspace unchanged (158 MB). 4 blocks/CU, VGPR ~60.
// Gate: gemm WRITE_SIZE must be exactly 131072 KB (spill detector).
// Numerics byte-identical (absmax 0.0): same per-chain MFMA order, exact
// fp64 a round-trip, conv/scan code untouched.

#define TT     256
#define KLEN   62
#define THETA  10.0

typedef int v4i __attribute__((ext_vector_type(4)));

// ===================== expand x -> i8 B-matrix (layer 1) ====================
// x: [32][1024][256] f32 {0,1}; bexp: [b][g=i/16][t][m=i%16] i8 {0,1}
__global__ __launch_bounds__(256)
void expand_x(const float* __restrict__ x, signed char* __restrict__ bexp)
{
    const int b = blockIdx.x;
    const int g = blockIdx.y;             // 64 groups of 16 inputs
    const int t = threadIdx.x;
    const float* xp = x + ((size_t)b*1024 + g*16)*TT + t;
    uint32_t uu[4];
    #pragma unroll
    for (int j = 0; j < 4; ++j) {
        uint32_t w = 0;
        #pragma unroll
        for (int m = 0; m < 4; ++m)
            w |= (xp[(size_t)(j*4 + m)*TT] >= 0.5f) ? (1u << (8*m)) : 0u;
        uu[j] = w;
    }
    *(uint4*)(bexp + (((size_t)b*64 + g)*256 + t)*16) = *(const uint4*)uu;
}

// ====================== weight -> int8 digit planes (swizzled) ==============
// planes: [oblk][s(I/64)][p(5)][lane(64)][16 B] -- MFMA A-frag register order:
// lane = quad*16+col holds digits of w[oblk*16+col][s*64 + quad*16 + 0..15].
__global__ __launch_bounds__(256)
void decompose_i8(const float* __restrict__ w, signed char* __restrict__ planes,
                  int I, int total)
{
    const int f = blockIdx.x * 256 + threadIdx.x;
    if (f >= total) return;
    const int NS = I / 64;
    const int per_oblk = NS * 5120;
    int rem  = f;
    const int oblk = rem / per_oblk;  rem -= oblk * per_oblk;
    const int s    = rem / 5120;      rem -= s * 5120;
    const int p    = rem >> 10;
    const int l    = (rem & 1023) >> 4;
    const int j    = rem & 15;
    const int quad = l >> 4, col = l & 15;
    const float wv = w[(size_t)(oblk*16 + col) * I + s*64 + quad*16 + j];
    long long v = llrint((double)wv * 274877906944.0);   // w * 2^38, exact int
    int d = 0;
    for (int q = 0; q <= p; ++q) {                       // balanced base-256
        d = (int)((v + 128) & 255) - 128;
        v = (v - d) >> 8;
    }
    planes[f] = (signed char)d;
}

// ============================ gemm-only kernel ==============================
// grid (B, O/16): b fastest (A-planes L2-hot). Two-pass acc[5][2] i8 MFMA
// over all 256 t -> exact fp64 recombine -> LDS transpose -> coalesced a
// store. No conv phase: live set ~90 VGPR; capped 128 -> 4 waves/SIMD.
template<int I>
__global__ __launch_bounds__(256) __attribute__((amdgpu_num_vgpr(128)))
void gemm_i8(const signed char* __restrict__ bexp,    // [b][I/16][256][16]
             const signed char* __restrict__ planes,  // swizzled A planes
             double*            __restrict__ au,      // [B][256][OS] (a out)
             int OS)
{
    constexpr int NS = I / 64;
    __shared__ double a_lds[257 * 17];                   // padded (row 256 unused)

    const int tid  = threadIdx.x;
    const int lane = tid & 63;
    const int wvu  = tid >> 6;
    const int quad = lane >> 4;
    const int col  = lane & 15;
    const int b    = blockIdx.x;
    const int oblk = blockIdx.y;
    const int o0   = oblk * 16;
    const int tw   = wvu * 64;

    const signed char* Apg = planes + (size_t)oblk * NS * 5120 + lane * 16;
    const double inv = 1.0 / 274877906944.0;             // 2^-38

    #pragma unroll 1
    for (int half = 0; half < 2; ++half) {
        const signed char* Bx = bexp +
            (((size_t)b*(I/16) + quad)*256 + tw + half*32 + col)*16;

        v4i acc[5][2];
        #pragma unroll
        for (int p = 0; p < 5; ++p)
            #pragma unroll
            for (int nt = 0; nt < 2; ++nt)
                acc[p][nt] = (v4i){0, 0, 0, 0};

        #pragma unroll 1
        for (int s = 0; s < NS; ++s) {
            v4i af[5];
            #pragma unroll
            for (int p = 0; p < 5; ++p)
                af[p] = *(const v4i*)(const void*)(Apg + (size_t)s * 5120 + p * 1024);
            v4i bf[2];
            #pragma unroll
            for (int nt = 0; nt < 2; ++nt)
                bf[nt] = *(const v4i*)(const void*)(Bx + (size_t)s * 16384 + nt * 256);

            #pragma unroll
            for (int nt = 0; nt < 2; ++nt)
                #pragma unroll
                for (int p = 0; p < 5; ++p)
                    acc[p][nt] = __builtin_amdgcn_mfma_i32_16x16x64_i8(
                                     af[p], bf[nt], acc[p][nt], 0, 0, 0);
        }

        // recombine: exact fp64 a into LDS (verified mapping)
        #pragma unroll
        for (int nt = 0; nt < 2; ++nt) {
            const int t = tw + half*32 + nt*16 + col;
            #pragma unroll
            for (int r = 0; r < 4; ++r) {
                double v =            (double)acc[4][nt][r];
                v = v * 256.0 + (double)acc[3][nt][r];
                v = v * 256.0 + (double)acc[2][nt][r];
                v = v * 256.0 + (double)acc[1][nt][r];
                v = v * 256.0 + (double)acc[0][nt][r];
                a_lds[t * 17 + quad*4 + r] = v * inv;
            }
        }
    }
    __syncthreads();

    // coalesced a store: 16 lanes x 8 B = 128 B contiguous per t-row
    for (int e = tid; e < 4096; e += 256) {
        const int row = e >> 4, oo = e & 15;
        au[((size_t)b * 256 + row) * OS + o0 + oo] = a_lds[row * 17 + oo];
    }
}

// ======================= conv kernel (in-place on au) =======================
// grid (B, O/16). Loads its [256 t][16 o] a-tile fully into LDS (barrier),
// runs the verified 61-tap FIR, stores u over the same addresses. Each block
// owns its slice exclusively -> in-place is race-free. 35 KB LDS ->
// 4 blocks/CU; low VGPR -> 4 waves/SIMD hides fp64 chains + LDS latency.
__global__ __launch_bounds__(256)
void conv_fir(double* au, int OS)
{
    __shared__ double a_lds[257 * 17];                   // 34.95 KB (row 256 = 0)
    __shared__ double srmE[68];

    const int tid  = threadIdx.x;
    const int b    = blockIdx.x;
    const int oblk = blockIdx.y;
    const int o0   = oblk * 16;

    if (tid < 68) {
        const int k = tid - 2;
        double v = 0.0;
        if (k >= 1 && k <= 61) {
            double wv = (double)k / 8.0 * exp(1.0 - (double)k / 8.0);
            v = (double)(float)wv;     // fp32-rounded tap, widened (R1-R17)
        }
        srmE[tid] = v;
    }

    // full tile load (coalesced: 16 lanes x 8 B = 128 B per t-row)
    for (int e = tid; e < 4096; e += 256) {
        const int row = e >> 4, oo = e & 15;
        a_lds[row * 17 + oo] = au[((size_t)b * 256 + row) * OS + o0 + oo];
    }
    if (tid < 17) a_lds[256 * 17 + tid] = 0.0;           // zero-guard row
    __syncthreads();

    // ---------------- conv: 61-tap FIR from LDS (verified) ------------------
    const int o    = tid & 15;
    const int tgrp = tid >> 4;                           // 0..15
    #pragma unroll
    for (int pass = 0; pass < 4; ++pass) {
        const int T0b = pass * 64 + tgrp * 4;
        double u0 = 0, u1 = 0, u2 = 0, u3 = 0;
        double w1 = srmE[64], w2 = srmE[65], w3 = srmE[66];   // zero pads
        for (int d = 0; d < 64; d += 4) {
            const int row = T0b - 61 + d;
            const int r0 = (row + 0 < 0) ? 256 : row + 0;
            const int r1 = (row + 1 < 0) ? 256 : row + 1;
            const int r2 = (row + 2 < 0) ? 256 : row + 2;
            const int r3 = (row + 3 < 0) ? 256 : row + 3;
            const double av0 = a_lds[r0 * 17 + o];
            const double av1 = a_lds[r1 * 17 + o];
            const double av2 = a_lds[r2 * 17 + o];
            const double av3 = a_lds[r3 * 17 + o];
            const double n0 = srmE[63 - d], n1 = srmE[62 - d];
            const double n2 = srmE[61 - d], n3 = srmE[60 - d];
            u0 = fma(n0, av0, u0); u1 = fma(w1, av0, u1); u2 = fma(w2, av0, u2); u3 = fma(w3, av0, u3);
            u0 = fma(n1, av1, u0); u1 = fma(n0, av1, u1); u2 = fma(w1, av1, u2); u3 = fma(w2, av1, u3);
            u0 = fma(n2, av2, u0); u1 = fma(n1, av2, u1); u2 = fma(n0, av2, u2); u3 = fma(w1, av2, u3);
            u0 = fma(n3, av3, u0); u1 = fma(n2, av3, u1); u2 = fma(n1, av3, u2); u3 = fma(n0, av3, u3);
            w1 = n3; w2 = n2; w3 = n1;
        }
        double* up = au + ((size_t)b * 256 + T0b) * OS + o0 + o;
        up[0]              = u0;
        up[(size_t)OS]     = u1;
        up[(size_t)OS * 2] = u2;
        up[(size_t)OS * 3] = u3;
    }
}

// ========================== scan (R8/R10-verified core) =====================
// lane = neuron; 256 sequential steps; refractory via 61-bit history mask.
// FINAL=false: ballots -> expanded i8 B-matrix bexp_out[b][g][t][m].
// FINAL=true:  f32 out[b][o][t].
template<bool FINAL>
__global__ __launch_bounds__(256)
void scan_spikes(const double* __restrict__ u, signed char* __restrict__ bexp_out,
                 float* __restrict__ f32_out, int OS)
{
    __shared__ double   ref64[KLEN];
    __shared__ uint32_t blds[8][256];   // 8 KB ballot staging
    const int tid = threadIdx.x;
    if (tid < KLEN) {
        double v = (double)tid / 8.0 * exp(1.0 - (double)tid / 8.0);
        ref64[tid] = (double)(float)(-20.0 * v);
    }
    __syncthreads();

    const int b     = blockIdx.y;
    const int obase = blockIdx.x * 256;
    const int o     = obase + tid;
    const int lane  = tid & 63;
    const int wv    = tid >> 6;
    const double* up = u + (size_t)b * TT * OS + o;

    uint64_t mask = 0;
    double cur0 = up[0], cur1 = up[OS], cur2 = up[2 * (size_t)OS], cur3 = up[3 * (size_t)OS];
    for (int t0 = 0; t0 < TT; t0 += 4) {
        double nx0 = 0, nx1 = 0, nx2 = 0, nx3 = 0;
        if (t0 + 4 < TT) {
            const double* pp = up + (size_t)(t0 + 4) * OS;
            nx0 = pp[0]; nx1 = pp[OS]; nx2 = pp[2 * (size_t)OS]; nx3 = pp[3 * (size_t)OS];
        }
        #pragma unroll
        for (int q = 0; q < 4; ++q) {
            const double uv = (q == 0) ? cur0 : (q == 1) ? cur1 : (q == 2) ? cur2 : cur3;
            uint64_t m = mask;
            double r0 = 0.0, r1 = 0.0;
            while (m) {
                int p = __builtin_ctzll(m); m &= m - 1;
                r0 += ref64[p + 1];
                if (m) { int pq = __builtin_ctzll(m); m &= m - 1; r1 += ref64[pq + 1]; }
            }
            const bool s = (uv + (r0 + r1)) >= THETA;
            const uint64_t bal = __ballot(s);
            if (lane == 0) {
                blds[wv * 2 + 0][t0 + q] = (uint32_t)bal;
                blds[wv * 2 + 1][t0 + q] = (uint32_t)(bal >> 32);
            }
            mask = ((mask << 1) | (s ? 1ull : 0ull)) & ((1ull << 61) - 1ull);
        }
        cur0 = nx0; cur1 = nx1; cur2 = nx2; cur3 = nx3;
    }
    __syncthreads();

    if (!FINAL) {
        // expand ballots to i8 B-matrix: entry g = obase/16 + gl, byte m =
        // bit ((gl&1)*16 + m) of word blds[gl>>1][t]  (i = g*16 + m)
        const int gbase = obase >> 4;
        for (int e = tid; e < 16 * 256; e += 256) {
            const int gl = e >> 8, t = e & 255;
            const uint32_t w = blds[gl >> 1][t];
            const uint32_t h = (w >> ((gl & 1) * 16)) & 0xFFFFu;
            uint32_t uu[4];
            #pragma unroll
            for (int j = 0; j < 4; ++j)
                uu[j] = (((h >> (4*j)) & 0xFu) * 0x00204081u) & 0x01010101u;
            *(uint4*)(bexp_out + (((size_t)b*128 + gbase + gl)*256 + t)*16) =
                *(const uint4*)uu;
        }
    } else {
        for (int ol = 0; ol < 256; ++ol) {
            const uint32_t w = blds[ol >> 5][tid];
            f32_out[((size_t)b * 512 + obase + ol) * TT + tid] =
                (float)((w >> (ol & 31)) & 1u);
        }
    }
}

// ================================ launcher ==================================
extern "C" void kernel_launch(void* const* d_in, const int* in_sizes, int n_in,
                              void* d_out, int out_size, void* d_ws, size_t ws_size,
                              hipStream_t stream)
{
    const float* x  = (const float*)d_in[0];   // [32][1024][256]
    const float* w1 = (const float*)d_in[1];   // [2048][1024]
    const float* w2 = (const float*)d_in[2];   // [512][2048]
    float* out = (float*)d_out;                // [32][512][256]

    char* ws = (char*)d_ws;
    // liveness-based layout (Bexp2 aliases dead P1/Bexp1): total ~158 MB
    signed char* P2    = (signed char*)ws;                      // 5.25 MB
    size_t roff = (size_t)32 * 32 * 5120;                       // 5242880
    signed char* P1    = (signed char*)(ws + roff);             // 10.5 MB
    signed char* Bexp1 = (signed char*)(ws + roff + (size_t)128*16*5120); // 8 MB
    signed char* Bexp2 = (signed char*)(ws + roff);             // 16 MB (alias)
    size_t uoff = roff + (size_t)128*16*5120 + (size_t)32*64*256*16; // 24117248
    double* au = (double*)(ws + uoff);          // 134 MB: a, then u in place

    expand_x<<<dim3(32, 64), 256, 0, stream>>>(x, Bexp1);
    decompose_i8<<<dim3((10485760 + 255)/256), 256, 0, stream>>>(w1, P1, 1024, 10485760);
    decompose_i8<<<dim3((5242880  + 255)/256), 256, 0, stream>>>(w2, P2, 2048, 5242880);

    // layer 1: 1024 -> 2048
    gemm_i8<1024><<<dim3(32, 128), 256, 0, stream>>>(Bexp1, P1, au, 2048);
    conv_fir<<<dim3(32, 128), 256, 0, stream>>>(au, 2048);
    scan_spikes<false><<<dim3(8, 32), 256, 0, stream>>>(au, Bexp2, nullptr, 2048);
    // layer 2: 2048 -> 512
    gemm_i8<2048><<<dim3(32, 32), 256, 0, stream>>>(Bexp2, P2, au, 512);
    conv_fir<<<dim3(32, 32), 256, 0, stream>>>(au, 512);
    scan_spikes<true><<<dim3(2, 32), 256, 0, stream>>>(au, nullptr, out, 512);
}